// Round 10
// baseline (38.663 us; speedup 1.0000x reference)
//
#include <hip/hip_runtime.h>
#include <math.h>

// x: [32,3,512,512] f32.
// Register-only row sweep, no LDS/barriers in stage 1.
// Each lane owns 8 cols (2 aligned float4 loads/row; wave spans 512 cols).
// Sobel separable via rolling vertical pair-sums: S = x[r-1]+x[r], X = x[r];
//   S2 = X + x[r+1]; a = S+S2 (vert [1,2,1]); b = S-S2 (vert [1,0,-1]);
//   gx = a(c-1)-a(c+1), gy = b(c-1)+2b(c)+b(c+1); mag = v_sqrt_f32.
// Horizontal halo via 4 shuffles per mag row + 2 per pool row.
// 8 output rows per wave -> 64 chunks/(b,c), 6144 waves (~6/SIMD, matching
// the VGPR-allowed occupancy; r9's 4224 waves under-filled it).
// Depth-1 double-buffered row prefetch hides VMEM latency under VALU.
// 64x8 = 512: every pool row is real -> no output-row masking at all.
// Grid: (16, 96) x 256.

__global__ __launch_bounds__(256) void sobel_pool_stats(
    const float* __restrict__ x, double* __restrict__ parts) {
  const int tid = threadIdx.x;
  const int lane = tid & 63;
  const int w = tid >> 6;
  const int bc = blockIdx.y;                 // 0..95
  const int chunk = blockIdx.x * 4 + w;      // 0..63
  const int row0 = chunk * 8;

  const float* __restrict__ xb = x + (size_t)bc * (512 * 512) + lane * 8;

  auto load8 = [&](int r, float* o) {
    if ((unsigned)r < 512u) {                // wave-uniform branch
      const float* p = xb + (size_t)r * 512;
      float4 u = *(const float4*)(p);
      float4 v = *(const float4*)(p + 4);
      o[0] = u.x; o[1] = u.y; o[2] = u.z; o[3] = u.w;
      o[4] = v.x; o[5] = v.y; o[6] = v.z; o[7] = v.w;
    } else {
#pragma unroll
      for (int k = 0; k < 8; ++k) o[k] = 0.f;
    }
  };

  float S[8], X[8];
  {
    float t0[8], t1[8];
    load8(row0 - 2, t0);
    load8(row0 - 1, t1);
#pragma unroll
    for (int k = 0; k < 8; ++k) { S[k] = t0[k] + t1[k]; X[k] = t1[k]; }
  }

  // Emit mag row rm from preloaded xn = x[rm+1]; advance S,X.
  auto magstep = [&](const float* xn, int rm, float* mg) {
    float S2[8];
#pragma unroll
    for (int k = 0; k < 8; ++k) S2[k] = X[k] + xn[k];
    if ((unsigned)rm < 512u) {               // wave-uniform
      float a[8], b[8];
#pragma unroll
      for (int k = 0; k < 8; ++k) { a[k] = S[k] + S2[k]; b[k] = S[k] - S2[k]; }
      float aL = __shfl_up(a[7], 1), aR = __shfl_down(a[0], 1);
      float bL = __shfl_up(b[7], 1), bR = __shfl_down(b[0], 1);
      if (lane == 0)  { aL = 0.f; bL = 0.f; }   // image col -1 = 0
      if (lane == 63) { aR = 0.f; bR = 0.f; }   // image col 512 = 0
#pragma unroll
      for (int j = 0; j < 8; ++j) {
        float am = j ? a[j - 1] : aL;
        float ap = (j < 7) ? a[j + 1] : aR;
        float bm = j ? b[j - 1] : bL;
        float bp = (j < 7) ? b[j + 1] : bR;
        float gx = am - ap;                      // horiz [1,0,-1]
        float gy = fmaf(2.f, b[j], bm + bp);     // horiz [1,2,1]
        float m2 = fmaf(gx, gx, 1e-6f);
        m2 = fmaf(gy, gy, m2);
        mg[j] = __builtin_amdgcn_sqrtf(m2);
      }
    } else {
#pragma unroll
      for (int j = 0; j < 8; ++j) mg[j] = 0.f;
    }
#pragma unroll
    for (int k = 0; k < 8; ++k) { S[k] = S2[k]; X[k] = xn[k]; }
  };

  // mag ring M[3][8], x ring xn[2][8]; all indices compile-time under unroll
  float M[3][8], xnb[2][8];
  load8(row0, xnb[0]);
  load8(row0 + 1, xnb[1]);
  magstep(xnb[0], row0 - 1, M[0]);           // mag[row0-1]
  load8(row0 + 2, xnb[0]);
  magstep(xnb[1], row0, M[1]);               // mag[row0]

  float s = 0.f, ss = 0.f;
#pragma unroll
  for (int i = 0; i < 8; ++i) {
    float* cur = xnb[i & 1];                 // holds x[row0+2+i]
    float* nxt = xnb[(i & 1) ^ 1];
    if (i < 7) load8(row0 + 3 + i, nxt);     // prefetch next iter's row
    float* MM = M[i % 3];
    float* MC = M[(i + 1) % 3];
    float* MP = M[(i + 2) % 3];
    magstep(cur, row0 + 1 + i, MP);          // mag[row0+1+i]

    float cs[8];
#pragma unroll
    for (int k = 0; k < 8; ++k) cs[k] = (MM[k] + MP[k]) + MC[k];
    float csL = __shfl_up(cs[7], 1), csR = __shfl_down(cs[0], 1);
    if (lane == 0) csL = 0.f;
    if (lane == 63) csR = 0.f;
#pragma unroll
    for (int j = 0; j < 8; ++j) {
      float cm = j ? cs[j - 1] : csL;
      float cp = (j < 7) ? cs[j + 1] : csR;
      float t = (cm + cp) + cs[j];
      s += t;
      ss = fmaf(t, t, ss);
    }
  }

  // per-wave double reduction; fold deferred /9, /81
  double ds = (double)s * (1.0 / 9.0);
  double dss = (double)ss * (1.0 / 81.0);
  for (int off = 32; off > 0; off >>= 1) {
    ds += __shfl_down(ds, off);
    dss += __shfl_down(dss, off);
  }
  if (lane == 0) {
    size_t idx = ((size_t)bc * 64 + chunk) * 2;
    parts[idx] = ds;
    parts[idx + 1] = dss;
  }
}

// Reduce 64 wave-partials per (b,c), feats [32,6]=[m0,s0,m1,s1,m2,s2], MLP.
__global__ __launch_bounds__(256) void stats_mlp(
    const double* __restrict__ parts,
    const float* __restrict__ w1, const float* __restrict__ b1,
    const float* __restrict__ w2, const float* __restrict__ b2,
    float* __restrict__ out) {
  __shared__ float feats[32 * 6];
  __shared__ float hbuf[32 * 32];
  const int tid = threadIdx.x;

  if (tid < 96) {
    int b = tid / 3;
    int ch = tid - b * 3;
    double s = 0.0, ss = 0.0;
    const double* p = parts + (size_t)tid * 128;  // 64 waves * 2 doubles
#pragma unroll
    for (int t = 0; t < 64; ++t) {
      s += p[2 * t];
      ss += p[2 * t + 1];
    }
    const double N = 262144.0;
    double mean = s / N;
    double var = (ss - s * s / N) / (N - 1.0);
    if (var < 0.0) var = 0.0;
    feats[b * 6 + 2 * ch] = (float)mean;
    feats[b * 6 + 2 * ch + 1] = (float)sqrt(var);
  }
  __syncthreads();

  for (int idx = tid; idx < 32 * 32; idx += 256) {
    int i = idx >> 5, j = idx & 31;
    float acc = b1[j];
#pragma unroll
    for (int k = 0; k < 6; ++k) acc += feats[i * 6 + k] * w1[j * 6 + k];
    hbuf[idx] = acc > 0.f ? acc : 0.f;
  }
  __syncthreads();

  for (int idx = tid; idx < 2048; idx += 256) {
    int i = idx >> 6, o = idx & 63;
    float acc = b2[o];
#pragma unroll
    for (int j = 0; j < 32; ++j) acc += hbuf[i * 32 + j] * w2[o * 32 + j];
    out[idx] = acc;
  }
}

extern "C" void kernel_launch(void* const* d_in, const int* in_sizes, int n_in,
                              void* d_out, int out_size, void* d_ws, size_t ws_size,
                              hipStream_t stream) {
  const float* x = (const float*)d_in[0];
  const float* w1 = (const float*)d_in[1];
  const float* b1 = (const float*)d_in[2];
  const float* w2 = (const float*)d_in[3];
  const float* b2 = (const float*)d_in[4];
  float* out = (float*)d_out;
  double* parts = (double*)d_ws;  // 96*64*2 doubles = 98304 B

  dim3 grid(16, 96);
  sobel_pool_stats<<<grid, 256, 0, stream>>>(x, parts);
  stats_mlp<<<1, 256, 0, stream>>>(parts, w1, b1, w2, b2, out);
}